// Round 1
// baseline (5318.097 us; speedup 1.0000x reference)
//
#include <hip/hip_runtime.h>

// ---- problem constants -----------------------------------------------------
#define PRECISE 1        // 1: bf16 hi/lo split (fp32-accurate), 0: plain bf16
#define BTOT   4096      // batch
#define TWARM  64        // warm timesteps
#define FIN    64        // input features
#define UDIM   256       // hidden units
#define ZDIM   1024      // 4*U gate pre-activations
#define KDIM   320       // FIN + UDIM (concat [x|h] @ [K;R])
#define OSTEPS 24
#define OCOLS  65        // dense out dim (F+1)
#define OCPAD  80        // padded to 5 col-tiles of 16
#define BR     32        // batch rows per block
#define ASTR   344       // LDS A row stride in bf16 (320 + 24 pad: 16B-aligned rows, 2-way banks)
#define NTHR   512       // 8 waves

typedef short bf16x8 __attribute__((ext_vector_type(8)));
typedef short s16x4  __attribute__((ext_vector_type(4)));
typedef float f32x4  __attribute__((ext_vector_type(4)));

static __device__ __forceinline__ short f2bf(float x) {  // RNE f32 -> bf16 bits
  unsigned u = __float_as_uint(x);
  return (short)((u + 0x7fffu + ((u >> 16) & 1u)) >> 16);
}
static __device__ __forceinline__ float bf2f(short h) {
  return __uint_as_float(((unsigned)(unsigned short)h) << 16);
}
static __device__ __forceinline__ float sigm(float x) {
  return 1.0f / (1.0f + __expf(-x));
}
static __device__ __forceinline__ float tanh_(float x) {
  return 2.0f / (1.0f + __expf(-2.0f * x)) - 1.0f;
}

// ---- weight repack: W[col][k] hi/lo bf16, k contiguous (B-fragment layout) --
__global__ void pack_w_kernel(const float* __restrict__ kern,
                              const float* __restrict__ rec,
                              short* __restrict__ Wh, short* __restrict__ Wl) {
  const int col = blockIdx.x;   // 0..1023
  const int k   = threadIdx.x;  // 0..319
  const float w = (k < FIN) ? kern[k * ZDIM + col] : rec[(k - FIN) * ZDIM + col];
  const short hi = f2bf(w);
  Wh[col * KDIM + k] = hi;
  Wl[col * KDIM + k] = f2bf(w - bf2f(hi));
}

__global__ void pack_dw_kernel(const float* __restrict__ dw,
                               short* __restrict__ Dh, short* __restrict__ Dl) {
  const int col = blockIdx.x;   // 0..79 (>=65 zero-padded)
  const int k   = threadIdx.x;  // 0..255
  const float w = (col < OCOLS) ? dw[k * OCOLS + col] : 0.0f;
  const short hi = f2bf(w);
  Dh[col * UDIM + k] = hi;
  Dl[col * UDIM + k] = f2bf(w - bf2f(hi));
}

// ---- persistent LSTM + autoregressive kernel -------------------------------
// grid 128 blocks x 512 thr; block owns 32 batch rows for all 88 steps.
// wave w computes gate cols {g*256 + w*32 + [0,32)} for g=i,f,g,o -> all 4
// gates of a hidden unit live in one wave's accumulators (reg-only fusion).
__global__ __launch_bounds__(NTHR, 2) void lstm_ar_kernel(
    const float* __restrict__ inputs, const float* __restrict__ bias,
    const float* __restrict__ dense_b, const short* __restrict__ Wh,
    const short* __restrict__ Wl, const short* __restrict__ Dh,
    const short* __restrict__ Dl, float* __restrict__ out) {
  __shared__ short Ah[BR * ASTR];   // A = [x(0:64) | h(64:320)] bf16 hi
  __shared__ short Al[BR * ASTR];   // bf16 lo residual

  const int tid  = (int)threadIdx.x;
  const int wv   = tid >> 6;        // wave 0..7
  const int lane = tid & 63;
  const int lrow = lane >> 4;       // k-group / row-group 0..3
  const int lcol = lane & 15;
  const int b0   = (int)blockIdx.x * BR;

  // per-lane gate bias: depends only on (ut, gate, lcol) -> 8 regs, reused all steps
  float bz[2][4];
#pragma unroll
  for (int ut = 0; ut < 2; ++ut)
#pragma unroll
    for (int g = 0; g < 4; ++g)
      bz[ut][g] = bias[g * UDIM + wv * 32 + ut * 16 + lcol];
  float dbz[5];
#pragma unroll
  for (int ct = 0; ct < 5; ++ct) {
    const int col = ct * 16 + lcol;
    dbz[ct] = (col < OCOLS) ? dense_b[col] : 0.0f;
  }

  // cell state in registers, MFMA C/D layout: (row = m*16+lrow*4+q, u = wv*32+ut*16+lcol)
  float cst[2][2][4] = {{{0.0f}}};

  // stage x_t (32 rows x 64 cols = 512 float4, one per thread)
  auto stage_x = [&](int t) {
    const int r  = tid >> 4;
    const int c4 = (tid & 15) << 2;
    const float4 v = *reinterpret_cast<const float4*>(
        inputs + (size_t)(b0 + r) * (TWARM * FIN) + (size_t)t * FIN + c4);
    s16x4 hi, lo;
    hi[0] = f2bf(v.x); lo[0] = f2bf(v.x - bf2f(hi[0]));
    hi[1] = f2bf(v.y); lo[1] = f2bf(v.y - bf2f(hi[1]));
    hi[2] = f2bf(v.z); lo[2] = f2bf(v.z - bf2f(hi[2]));
    hi[3] = f2bf(v.w); lo[3] = f2bf(v.w - bf2f(hi[3]));
    *reinterpret_cast<s16x4*>(&Ah[r * ASTR + c4]) = hi;
    *reinterpret_cast<s16x4*>(&Al[r * ASTR + c4]) = lo;
  };

  // one LSTM step: z = [x|h] @ [K;R] + b  (MFMA), then gate fusion in regs,
  // h written back to LDS as bf16 hi/lo. Ends with writers-side work done;
  // caller must __syncthreads() before the next consumer.
  auto lstm_step = [&]() {
    f32x4 acc[2][2][4];
#pragma unroll
    for (int m = 0; m < 2; ++m)
#pragma unroll
      for (int ut = 0; ut < 2; ++ut)
#pragma unroll
        for (int g = 0; g < 4; ++g) {
          acc[m][ut][g][0] = bz[ut][g]; acc[m][ut][g][1] = bz[ut][g];
          acc[m][ut][g][2] = bz[ut][g]; acc[m][ut][g][3] = bz[ut][g];
        }
#pragma unroll
    for (int kt = 0; kt < 10; ++kt) {
      const int k0 = kt * 32;
      bf16x8 ah[2], al[2];
#pragma unroll
      for (int m = 0; m < 2; ++m) {
        const int aoff = (m * 16 + lcol) * ASTR + k0 + lrow * 8;
        ah[m] = *reinterpret_cast<const bf16x8*>(&Ah[aoff]);
        al[m] = *reinterpret_cast<const bf16x8*>(&Al[aoff]);
      }
#pragma unroll
      for (int ct = 0; ct < 8; ++ct) {
        const int g = ct >> 1, ut = ct & 1;
        const int woff = (g * UDIM + wv * 32 + ut * 16 + lcol) * KDIM + k0 + lrow * 8;
        const bf16x8 bh = *reinterpret_cast<const bf16x8*>(Wh + woff);
#if PRECISE
        const bf16x8 bl = *reinterpret_cast<const bf16x8*>(Wl + woff);
#endif
#pragma unroll
        for (int m = 0; m < 2; ++m) {
          acc[m][ut][g] = __builtin_amdgcn_mfma_f32_16x16x32_bf16(ah[m], bh, acc[m][ut][g], 0, 0, 0);
#if PRECISE
          acc[m][ut][g] = __builtin_amdgcn_mfma_f32_16x16x32_bf16(al[m], bh, acc[m][ut][g], 0, 0, 0);
          acc[m][ut][g] = __builtin_amdgcn_mfma_f32_16x16x32_bf16(ah[m], bl, acc[m][ut][g], 0, 0, 0);
#endif
        }
      }
    }
    __syncthreads();  // all waves done reading A before h is overwritten
#pragma unroll
    for (int m = 0; m < 2; ++m)
#pragma unroll
      for (int ut = 0; ut < 2; ++ut)
#pragma unroll
        for (int q = 0; q < 4; ++q) {
          const float iv = sigm(acc[m][ut][0][q]);
          const float fv = sigm(acc[m][ut][1][q]);
          const float gv = tanh_(acc[m][ut][2][q]);
          const float ov = sigm(acc[m][ut][3][q]);
          const float c  = fv * cst[m][ut][q] + iv * gv;
          cst[m][ut][q]  = c;
          const float h  = ov * tanh_(c);
          const int row  = m * 16 + lrow * 4 + q;
          const int u    = wv * 32 + ut * 16 + lcol;
          const short hi = f2bf(h);
          Ah[row * ASTR + FIN + u] = hi;
          Al[row * ASTR + FIN + u] = f2bf(h - bf2f(hi));
        }
  };

  // init: zero A (h0 = 0), then stage x_0
  for (int i = tid; i < BR * ASTR; i += NTHR) { Ah[i] = 0; Al[i] = 0; }
  __syncthreads();
  stage_x(0);
  __syncthreads();

  // ---- warm phase ----
#pragma unroll 1
  for (int t = 0; t < TWARM; ++t) {
    lstm_step();
    if (t + 1 < TWARM) stage_x(t + 1);   // x writes disjoint from h writes
    __syncthreads();
  }

  // ---- autoregressive phase ----
#pragma unroll 1
  for (int s = 0; s < OSTEPS; ++s) {
    // dense: pred = h @ Dw + db on waves 0,1 (wave m handles M-tile m).
    // reads A k=64..319, writes A k=0..63 (disjoint) + out column.
    if (wv < 2) {
      const int m = wv;
      f32x4 p[5];
#pragma unroll
      for (int ct = 0; ct < 5; ++ct) {
        p[ct][0] = dbz[ct]; p[ct][1] = dbz[ct]; p[ct][2] = dbz[ct]; p[ct][3] = dbz[ct];
      }
#pragma unroll
      for (int kt = 0; kt < 8; ++kt) {
        const int k0   = FIN + kt * 32;
        const int aoff = (m * 16 + lcol) * ASTR + k0 + lrow * 8;
        const bf16x8 ah = *reinterpret_cast<const bf16x8*>(&Ah[aoff]);
#if PRECISE
        const bf16x8 al = *reinterpret_cast<const bf16x8*>(&Al[aoff]);
#endif
#pragma unroll
        for (int ct = 0; ct < 5; ++ct) {
          const int doff = (ct * 16 + lcol) * UDIM + kt * 32 + lrow * 8;
          const bf16x8 bh = *reinterpret_cast<const bf16x8*>(Dh + doff);
          p[ct] = __builtin_amdgcn_mfma_f32_16x16x32_bf16(ah, bh, p[ct], 0, 0, 0);
#if PRECISE
          const bf16x8 bl = *reinterpret_cast<const bf16x8*>(Dl + doff);
          p[ct] = __builtin_amdgcn_mfma_f32_16x16x32_bf16(al, bh, p[ct], 0, 0, 0);
          p[ct] = __builtin_amdgcn_mfma_f32_16x16x32_bf16(ah, bl, p[ct], 0, 0, 0);
#endif
        }
      }
      // x_next = pred[:, 0:64] -> A staging (k = col)
#pragma unroll
      for (int ct = 0; ct < 4; ++ct)
#pragma unroll
        for (int q = 0; q < 4; ++q) {
          const float v  = p[ct][q];
          const int row  = m * 16 + lrow * 4 + q;
          const int col  = ct * 16 + lcol;
          const short hi = f2bf(v);
          Ah[row * ASTR + col] = hi;
          Al[row * ASTR + col] = f2bf(v - bf2f(hi));
        }
      // out[:, s] = pred[:, 64]  (col-tile 4, lcol==0)
      if (lcol == 0) {
#pragma unroll
        for (int q = 0; q < 4; ++q)
          out[(size_t)(b0 + m * 16 + lrow * 4 + q) * OSTEPS + s] = p[4][q];
      }
    }
    __syncthreads();
    if (s + 1 < OSTEPS) {
      lstm_step();
      __syncthreads();
    }
  }
}

// ---- launch ---------------------------------------------------------------
extern "C" void kernel_launch(void* const* d_in, const int* in_sizes, int n_in,
                              void* d_out, int out_size, void* d_ws, size_t ws_size,
                              hipStream_t stream) {
  (void)in_sizes; (void)n_in; (void)out_size; (void)ws_size;
  const float* inputs = (const float*)d_in[0];
  const float* kern   = (const float*)d_in[1];
  const float* rec    = (const float*)d_in[2];
  const float* bias   = (const float*)d_in[3];
  const float* dw     = (const float*)d_in[4];
  const float* db     = (const float*)d_in[5];
  float* out = (float*)d_out;

  short* Wh = (short*)d_ws;              // 1024*320 bf16
  short* Wl = Wh + ZDIM * KDIM;          // 1024*320
  short* Dh = Wl + ZDIM * KDIM;          // 80*256
  short* Dl = Dh + OCPAD * UDIM;         // 80*256   (total ~1.33 MB of ws)

  hipLaunchKernelGGL(pack_w_kernel,  dim3(ZDIM),  dim3(KDIM), 0, stream, kern, rec, Wh, Wl);
  hipLaunchKernelGGL(pack_dw_kernel, dim3(OCPAD), dim3(UDIM), 0, stream, dw, Dh, Dl);
  hipLaunchKernelGGL(lstm_ar_kernel, dim3(BTOT / BR), dim3(NTHR), 0, stream,
                     inputs, bias, db, Wh, Wl, Dh, Dl, out);
}